// Round 1
// baseline (1009.672 us; speedup 1.0000x reference)
//
#include <hip/hip_runtime.h>
#include <math.h>

// Problem constants
#define Cc 512          // feature dim
#define Pp 1024         // centroids
#define TM 32           // rows per block
#define TP 256          // centroid tile (looped)
#define BK 32           // K tile

// ---------------------------------------------------------------------------
// Pre-kernel: centroid squared norms -> d_ws[0..1023]
// ---------------------------------------------------------------------------
__global__ __launch_bounds__(256) void cnorm_kernel(const float* __restrict__ cent,
                                                    float* __restrict__ cnorm) {
    int wid  = blockIdx.x * 4 + (threadIdx.x >> 6);   // one wave per centroid
    int lane = threadIdx.x & 63;
    const float4* r = (const float4*)(cent + (size_t)wid * Cc);
    float4 a = r[lane * 2];
    float4 b = r[lane * 2 + 1];
    float s = a.x*a.x + a.y*a.y + a.z*a.z + a.w*a.w
            + b.x*b.x + b.y*b.y + b.z*b.z + b.w*b.w;
    #pragma unroll
    for (int m = 1; m < 64; m <<= 1) s += __shfl_xor(s, m);
    if (lane == 0) cnorm[wid] = s;
}

// branch-free sorted insert of v into (t0 <= t1 <= t2), keeping smallest 3
#define TOP3_INSERT(t0, t1, t2, v)                                  \
    do {                                                            \
        float _n0 = fminf((t0), (v));                               \
        float _h0 = fmaxf((t0), (v));                               \
        float _n1 = fminf((t1), _h0);                               \
        float _h1 = fmaxf((t1), _h0);                               \
        float _n2 = fminf((t2), _h1);                               \
        (t0) = _n0; (t1) = _n1; (t2) = _n2;                         \
    } while (0)

// ---------------------------------------------------------------------------
// Main kernel: fused distances + top-3 smallest + softmin score
// Each block: 32 rows, all 1024 centroids (P looped in tiles of 256).
// Threads: tid = ty*64 + tx;  ty in [0,4) owns rows ty*8+i;  tx in [0,64)
// owns cols tx*4+j of the current P tile.
// ---------------------------------------------------------------------------
__global__ __launch_bounds__(256) void dist_topk_kernel(
        const float* __restrict__ E, const float* __restrict__ Ct,
        const float* __restrict__ cnorm, float* __restrict__ out) {
    __shared__ float As[TM][BK + 4];     // +4 pad keeps float4 alignment, breaks bank stride
    __shared__ float Bs[BK][TP + 4];     // k-major: Bs[k][c] = Ct[pt+c][kk+k]

    const int tid  = threadIdx.x;
    const int tx   = tid & 63;
    const int ty   = tid >> 6;
    const int row0 = blockIdx.x * TM;

    float top0[8], top1[8], top2[8];
    float fnorm[8];
    #pragma unroll
    for (int i = 0; i < 8; ++i) {
        top0[i] = 1e30f; top1[i] = 1e30f; top2[i] = 1e30f;
        fnorm[i] = 0.f;
    }

    // staging indices (independent of tx/ty mapping)
    const int sr = tid >> 3;            // 0..31
    const int sk = (tid & 7) * 4;       // 0,4,...,28
    const float* Abase = E + (size_t)(row0 + sr) * Cc + sk;

    for (int pt = 0; pt < Pp; pt += TP) {
        float acc[8][4];
        #pragma unroll
        for (int i = 0; i < 8; ++i)
            #pragma unroll
            for (int j = 0; j < 4; ++j) acc[i][j] = 0.f;

        for (int kk = 0; kk < Cc; kk += BK) {
            __syncthreads();   // protect previous tile's reads
            // stage A tile [32][32]: one float4 per thread, 128B segments
            float4 ga = *(const float4*)(Abase + kk);
            *(float4*)&As[sr][sk] = ga;
            // stage B tile [32][256] transposed to k-major: 8 float4 per thread
            #pragma unroll
            for (int q = 0; q < 8; ++q) {
                int c = sr + 32 * q;
                float4 gb = *(const float4*)(Ct + (size_t)(pt + c) * Cc + kk + sk);
                Bs[sk + 0][c] = gb.x;
                Bs[sk + 1][c] = gb.y;
                Bs[sk + 2][c] = gb.z;
                Bs[sk + 3][c] = gb.w;
            }
            __syncthreads();

            #pragma unroll
            for (int k4 = 0; k4 < BK; k4 += 4) {
                float4 av[8];
                #pragma unroll
                for (int i = 0; i < 8; ++i)
                    av[i] = *(const float4*)&As[ty * 8 + i][k4];   // wave-uniform broadcast
                if (pt == 0) {   // accumulate row norms for free (first P tile only)
                    #pragma unroll
                    for (int i = 0; i < 8; ++i)
                        fnorm[i] += av[i].x*av[i].x + av[i].y*av[i].y
                                  + av[i].z*av[i].z + av[i].w*av[i].w;
                }
                #pragma unroll
                for (int k2 = 0; k2 < 4; ++k2) {
                    float4 bv = *(const float4*)&Bs[k4 + k2][tx * 4];  // contiguous wave b128
                    #pragma unroll
                    for (int i = 0; i < 8; ++i) {
                        float a = ((const float*)&av[i])[k2];
                        acc[i][0] = fmaf(a, bv.x, acc[i][0]);
                        acc[i][1] = fmaf(a, bv.y, acc[i][1]);
                        acc[i][2] = fmaf(a, bv.z, acc[i][2]);
                        acc[i][3] = fmaf(a, bv.w, acc[i][3]);
                    }
                }
            }
        }

        // epilogue for this P tile: squared distances -> running top-3
        float cn[4];
        #pragma unroll
        for (int j = 0; j < 4; ++j) cn[j] = cnorm[pt + tx * 4 + j];
        #pragma unroll
        for (int i = 0; i < 8; ++i) {
            #pragma unroll
            for (int j = 0; j < 4; ++j) {
                float v = fnorm[i] + cn[j] - 2.f * acc[i][j];
                TOP3_INSERT(top0[i], top1[i], top2[i], v);
            }
        }
    }

    // merge top-3 across the 64 lanes of the wave (all share rows ty*8+i)
    #pragma unroll
    for (int m = 1; m <= 32; m <<= 1) {
        #pragma unroll
        for (int i = 0; i < 8; ++i) {
            float o0 = __shfl_xor(top0[i], m);
            float o1 = __shfl_xor(top1[i], m);
            float o2 = __shfl_xor(top2[i], m);
            TOP3_INSERT(top0[i], top1[i], top2[i], o0);
            TOP3_INSERT(top0[i], top1[i], top2[i], o1);
            TOP3_INSERT(top0[i], top1[i], top2[i], o2);
        }
    }

    if (tx == 0) {
        #pragma unroll
        for (int i = 0; i < 8; ++i) {
            float d0 = sqrtf(top0[i]);
            float d1 = sqrtf(top1[i]);
            float d2 = sqrtf(top2[i]);
            // softmax(-d)[0] = 1 / (1 + e^(d0-d1) + e^(d0-d2)); exponents <= 0
            float w0 = 1.f / (1.f + __expf(d0 - d1) + __expf(d0 - d2));
            out[row0 + ty * 8 + i] = w0 * d0;
        }
    }
}

extern "C" void kernel_launch(void* const* d_in, const int* in_sizes, int n_in,
                              void* d_out, int out_size, void* d_ws, size_t ws_size,
                              hipStream_t stream) {
    (void)in_sizes; (void)n_in; (void)out_size; (void)ws_size;
    const float* embeds    = (const float*)d_in[0];   // [8,3136,512] fp32
    const float* centroids = (const float*)d_in[1];   // [1024,512]  fp32
    float* cnorm = (float*)d_ws;                      // 1024 floats scratch
    float* out   = (float*)d_out;                     // [8,1,56,56] = 25088 fp32

    cnorm_kernel<<<Pp / 4, 256, 0, stream>>>(centroids, cnorm);
    dist_topk_kernel<<<(8 * 3136) / TM, 256, 0, stream>>>(embeds, centroids, cnorm, out);
}

// Round 2
// 75.166 us; speedup vs baseline: 13.4325x; 13.4325x over previous
//
#include <hip/hip_runtime.h>
#include <math.h>

#define Cc 512
#define Pp 1024
#define NROW 25088      // B*N = 8*3136
#define BM 64
#define BN 256
#define BK 32

typedef short  bf16x8 __attribute__((ext_vector_type(8)));   // 8 bf16 = 4 VGPR
typedef float  f32x4  __attribute__((ext_vector_type(4)));
typedef unsigned short u16x8 __attribute__((ext_vector_type(8)));

__device__ __forceinline__ unsigned short bf16_rne(float f) {
    unsigned int u = __float_as_uint(f);
    return (unsigned short)((u + 0x7fffu + ((u >> 16) & 1u)) >> 16);
}

// ---------------------------------------------------------------------------
// Fused fp32 -> bf16 (RNE) conversion + row squared-norm. One wave per row
// of 512 floats. Used for both embeds (25088 rows) and centroids (1024 rows).
// ---------------------------------------------------------------------------
__global__ __launch_bounds__(256) void conv_norm_kernel(
        const float* __restrict__ src, unsigned short* __restrict__ dst,
        float* __restrict__ nrm) {
    int wid  = blockIdx.x * 4 + (threadIdx.x >> 6);
    int lane = threadIdx.x & 63;
    const float4* r = (const float4*)(src + (size_t)wid * Cc);
    float4 a = r[lane * 2];
    float4 b = r[lane * 2 + 1];
    u16x8 o;
    o[0] = bf16_rne(a.x); o[1] = bf16_rne(a.y); o[2] = bf16_rne(a.z); o[3] = bf16_rne(a.w);
    o[4] = bf16_rne(b.x); o[5] = bf16_rne(b.y); o[6] = bf16_rne(b.z); o[7] = bf16_rne(b.w);
    *(u16x8*)(dst + (size_t)wid * Cc + lane * 8) = o;
    float s = a.x*a.x + a.y*a.y + a.z*a.z + a.w*a.w
            + b.x*b.x + b.y*b.y + b.z*b.z + b.w*b.w;
    #pragma unroll
    for (int m = 1; m < 64; m <<= 1) s += __shfl_xor(s, m);
    if (lane == 0) nrm[wid] = s;
}

// branch-free sorted insert of v into (t0 <= t1 <= t2), keeping smallest 3
#define TOP3_INSERT(t0, t1, t2, v)                                  \
    do {                                                            \
        float _n0 = fminf((t0), (v));                               \
        float _h0 = fmaxf((t0), (v));                               \
        float _n1 = fminf((t1), _h0);                               \
        float _h1 = fmaxf((t1), _h0);                               \
        float _n2 = fminf((t2), _h1);                               \
        (t0) = _n0; (t1) = _n1; (t2) = _n2;                         \
    } while (0)

#define GLOAD_LDS16(gp, lp)                                             \
    __builtin_amdgcn_global_load_lds(                                   \
        (const __attribute__((address_space(1))) void*)(const void*)(gp),\
        (__attribute__((address_space(3))) void*)(void*)(lp), 16, 0, 0)

// ---------------------------------------------------------------------------
// Main: bf16 MFMA distance GEMM fused with top-3-smallest + softmin score.
// Block: 64 rows; loops P in 4 tiles of 256. 512 threads = 8 waves (2x4).
// Wave tile 32x64 = 2(m) x 4(n) fragments of 16x16x32.
// ---------------------------------------------------------------------------
__global__ __launch_bounds__(512, 2) void mfma_topk_kernel(
        const unsigned short* __restrict__ Eb, const unsigned short* __restrict__ Cb,
        const float* __restrict__ fnorm, const float* __restrict__ cnorm,
        float* __restrict__ out) {
    __shared__ unsigned short smem[(BM + BN) * BK];   // A(64x32) then B(256x32), 20KB
    __shared__ float tops[2][4][32][3];               // per-(wy,wx) row top3, 3KB

    const int tid  = threadIdx.x;
    const int w    = tid >> 6;
    const int lane = tid & 63;
    const int wy   = w >> 2;        // 0..1  row half
    const int wx   = w & 3;         // 0..3  col quarter
    const int g    = lane >> 4;     // 0..3
    const int q    = lane & 15;     // 0..15
    const int row0 = blockIdx.x * BM;

    // per-lane row norms for its 8 (m,r) row slots
    float fn[2][4];
    #pragma unroll
    for (int m = 0; m < 2; ++m)
        #pragma unroll
        for (int r = 0; r < 4; ++r)
            fn[m][r] = fnorm[row0 + wy * 32 + m * 16 + g * 4 + r];

    float t0[2][4], t1[2][4], t2[2][4];
    #pragma unroll
    for (int m = 0; m < 2; ++m)
        #pragma unroll
        for (int r = 0; r < 4; ++r) { t0[m][r] = 1e30f; t1[m][r] = 1e30f; t2[m][r] = 1e30f; }

    unsigned short* As = smem;                // [64][32]
    unsigned short* Bs = smem + BM * BK;      // [256][32]

    for (int pt = 0; pt < Pp; pt += BN) {
        f32x4 acc[2][4];
        #pragma unroll
        for (int m = 0; m < 2; ++m)
            #pragma unroll
            for (int n = 0; n < 4; ++n) acc[m][n] = (f32x4){0.f, 0.f, 0.f, 0.f};

        for (int kk = 0; kk < Cc; kk += BK) {
            __syncthreads();    // previous tile's reads done
            // stage A (256 chunks of 16B) + B (1024 chunks), linear chunk map
            #pragma unroll
            for (int it = 0; it < 3; ++it) {
                int c = tid + it * 512;
                if (c < (BM + BN) * BK / 8) {          // 1280 chunks
                    const unsigned short* gsrc;
                    if (c < BM * BK / 8) {             // A: 256 chunks
                        int row = c >> 2, kc = c & 3;
                        gsrc = Eb + (size_t)(row0 + row) * Cc + kk + kc * 8;
                    } else {
                        int b = c - BM * BK / 8;       // B: 1024 chunks
                        int col = b >> 2, kc = b & 3;
                        gsrc = Cb + (size_t)(pt + col) * Cc + kk + kc * 8;
                    }
                    GLOAD_LDS16(gsrc, (char*)smem + c * 16);
                }
            }
            __syncthreads();    // staging complete (drains vmcnt)

            bf16x8 a[2], b[4];
            #pragma unroll
            for (int m = 0; m < 2; ++m)
                a[m] = *(const bf16x8*)(As + (wy * 32 + m * 16 + q) * BK + g * 8);
            #pragma unroll
            for (int n = 0; n < 4; ++n)
                b[n] = *(const bf16x8*)(Bs + (wx * 64 + n * 16 + q) * BK + g * 8);
            #pragma unroll
            for (int m = 0; m < 2; ++m)
                #pragma unroll
                for (int n = 0; n < 4; ++n)
                    acc[m][n] = __builtin_amdgcn_mfma_f32_16x16x32_bf16(
                        a[m], b[n], acc[m][n], 0, 0, 0);
        }

        // epilogue: distances -> running top3
        float cn[4];
        #pragma unroll
        for (int n = 0; n < 4; ++n) cn[n] = cnorm[pt + wx * 64 + n * 16 + q];
        #pragma unroll
        for (int m = 0; m < 2; ++m)
            #pragma unroll
            for (int n = 0; n < 4; ++n)
                #pragma unroll
                for (int r = 0; r < 4; ++r) {
                    float v = fn[m][r] + cn[n] - 2.f * acc[m][n][r];
                    TOP3_INSERT(t0[m][r], t1[m][r], t2[m][r], v);
                }
    }

    // merge across the 16-lane col group (q = lane&15; rows depend only on g)
    #pragma unroll
    for (int mask = 1; mask <= 8; mask <<= 1) {
        #pragma unroll
        for (int m = 0; m < 2; ++m)
            #pragma unroll
            for (int r = 0; r < 4; ++r) {
                float o0 = __shfl_xor(t0[m][r], mask);
                float o1 = __shfl_xor(t1[m][r], mask);
                float o2 = __shfl_xor(t2[m][r], mask);
                TOP3_INSERT(t0[m][r], t1[m][r], t2[m][r], o0);
                TOP3_INSERT(t0[m][r], t1[m][r], t2[m][r], o1);
                TOP3_INSERT(t0[m][r], t1[m][r], t2[m][r], o2);
            }
    }

    if (q == 0) {
        #pragma unroll
        for (int m = 0; m < 2; ++m)
            #pragma unroll
            for (int r = 0; r < 4; ++r) {
                int rl = m * 16 + g * 4 + r;
                tops[wy][wx][rl][0] = t0[m][r];
                tops[wy][wx][rl][1] = t1[m][r];
                tops[wy][wx][rl][2] = t2[m][r];
            }
    }
    __syncthreads();

    if (tid < BM) {
        int wy2 = tid >> 5, rl = tid & 31;
        float a0 = tops[wy2][0][rl][0];
        float a1 = tops[wy2][0][rl][1];
        float a2 = tops[wy2][0][rl][2];
        #pragma unroll
        for (int x = 1; x < 4; ++x) {
            TOP3_INSERT(a0, a1, a2, tops[wy2][x][rl][0]);
            TOP3_INSERT(a0, a1, a2, tops[wy2][x][rl][1]);
            TOP3_INSERT(a0, a1, a2, tops[wy2][x][rl][2]);
        }
        float d0 = sqrtf(fmaxf(a0, 0.f));
        float d1 = sqrtf(fmaxf(a1, 0.f));
        float d2 = sqrtf(fmaxf(a2, 0.f));
        float w0 = 1.f / (1.f + __expf(d0 - d1) + __expf(d0 - d2));
        out[row0 + wy2 * 32 + rl] = w0 * d0;
    }
}

extern "C" void kernel_launch(void* const* d_in, const int* in_sizes, int n_in,
                              void* d_out, int out_size, void* d_ws, size_t ws_size,
                              hipStream_t stream) {
    (void)in_sizes; (void)n_in; (void)out_size; (void)ws_size;
    const float* embeds    = (const float*)d_in[0];   // [8,3136,512] fp32
    const float* centroids = (const float*)d_in[1];   // [1024,512]  fp32
    float* out = (float*)d_out;

    // workspace layout (bytes): cnorm[1024]f32 @0, fnorm[25088]f32 @4096,
    // Eb bf16 @131072 (25,690,112 B), Cb bf16 @25,821,184 (1 MB) -> ~25.6 MB
    char* ws = (char*)d_ws;
    float*          cnorm = (float*)(ws);
    float*          fnorm = (float*)(ws + 4096);
    unsigned short* Eb    = (unsigned short*)(ws + 131072);
    unsigned short* Cb    = (unsigned short*)(ws + 131072 + (size_t)NROW * Cc * 2);

    conv_norm_kernel<<<NROW / 4, 256, 0, stream>>>(embeds, Eb, fnorm);
    conv_norm_kernel<<<Pp / 4,   256, 0, stream>>>(centroids, Cb, cnorm);
    mfma_topk_kernel<<<NROW / BM, 512, 0, stream>>>(Eb, Cb, fnorm, cnorm, out);
}